// Round 1
// 467.963 us; speedup vs baseline: 1.0362x; 1.0362x over previous
//
#include <hip/hip_runtime.h>

// Problem constants (from reference): V=C=8192, B=8, T=1024.
#define V 8192
#define B 8
#define T 1024
#define NSEG 16          // T split into 16 segments of 64
#define SEGLEN 64
#define CSLICE 1024      // channels per sum-block (256 thr * float4)
#define NCHUNK 32        // LSE chunks of 256 channels (64 lanes * float4)
#define CHUNK 256

typedef float f32x4 __attribute__((ext_vector_type(4)));

// Non-temporal 16B store: logits is write-once, never re-read by us.
// Bypassing the 256MB LLC keeps emb rows resident for the pass-2 gather.
__device__ __forceinline__ void nt_store4(float4* p, float4 v) {
    __builtin_nontemporal_store(*(f32x4*)&v, (f32x4*)p);
}

// Pass 1 (read-only): per-segment per-channel sums of the gathered rows.
// grid (V/CSLICE=8, NSEG=16, B=8), block 256.
// Latency fix: the 64 row indices are preloaded one-per-lane and broadcast
// with __shfl (fully unrolled -> readlane), and a 4-deep prefetch ring keeps
// 4 gathers in flight per wave instead of serializing index-load -> gather.
__global__ __launch_bounds__(256) void sum_kernel(
    const float* __restrict__ emb, const int* __restrict__ x,
    float* __restrict__ segsum)
{
    const int slice = blockIdx.x;
    const int seg   = blockIdx.y;
    const int b     = blockIdx.z;
    const int lane  = threadIdx.x & 63;
    const int c4    = (slice * CSLICE + threadIdx.x * 4) >> 2;

    const int xi = x[b * T + seg * SEGLEN + lane];   // lane i holds row for t=i

    const float4* emb4 = (const float4*)emb;
    float4 acc = make_float4(0.f, 0.f, 0.f, 0.f);
    float4 vbuf[4];
#pragma unroll
    for (int k = 0; k < 4; ++k)
        vbuf[k] = emb4[(size_t)__shfl(xi, k, 64) * (V / 4) + c4];

#pragma unroll
    for (int i = 0; i < SEGLEN; i += 4) {
#pragma unroll
        for (int k = 0; k < 4; ++k) {
            float4 cur = vbuf[k];
            const int nxt = i + 4 + k;
            if (nxt < SEGLEN)
                vbuf[k] = emb4[(size_t)__shfl(xi, nxt, 64) * (V / 4) + c4];
            acc.x += cur.x; acc.y += cur.y; acc.z += cur.z; acc.w += cur.w;
        }
    }
    ((float4*)segsum)[(size_t)(b * NSEG + seg) * (V / 4) + c4] = acc;
}

// Pass 2 (fused gather + logits write + LSE): per wave = one (b, 256-ch
// chunk, 64-t segment). Carry-in from segsum (ascending order: bit-identical
// to baseline), then walk the segment with a 4-deep prefetch ring.
// grid (NCHUNK/4=8, NSEG=16, B=8), block 256 (4 waves).
__global__ __launch_bounds__(256) void fused_kernel(
    const float* __restrict__ emb, const int* __restrict__ x,
    const int* __restrict__ y, const float* __restrict__ segsum,
    float* __restrict__ logits, float* __restrict__ P, float* __restrict__ tval)
{
    const int wave  = threadIdx.x >> 6;
    const int lane  = threadIdx.x & 63;
    const int chunk = blockIdx.x * 4 + wave;          // 0..31
    const int seg   = blockIdx.y;
    const int b     = blockIdx.z;
    const int c0    = chunk * CHUNK + lane * 4;
    const int c4    = c0 >> 2;
    const int tbase = seg * SEGLEN;

    const float4* ss4 = (const float4*)segsum;
    float4 S = make_float4(0.f, 0.f, 0.f, 0.f);
    for (int s = 0; s < seg; ++s) {                   // exclusive carry-in
        float4 v = ss4[(size_t)(b * NSEG + s) * (V / 4) + c4];
        S.x += v.x; S.y += v.y; S.z += v.z; S.w += v.w;
    }

    // Per-lane preload: indices and 1/(t+1). invi is the IDENTICAL
    // expression the baseline evaluated per-t (same bits), just computed
    // once on lane t-tbase and broadcast.
    const int   xi   = x[b * T + tbase + lane];
    const int   yi   = y[b * T + tbase + lane];
    const float invi = 1.0f / (float)(tbase + lane + 1);

    const float4* emb4    = (const float4*)emb;
    float4*       logits4 = (float4*)logits;

    float4 vbuf[4];
#pragma unroll
    for (int k = 0; k < 4; ++k)
        vbuf[k] = emb4[(size_t)__shfl(xi, k, 64) * (V / 4) + c4];

    float myP = 0.f;                                  // lane i keeps denom of t=tbase+i
    for (int i = 0; i < SEGLEN; i += 4) {
#pragma unroll
        for (int k = 0; k < 4; ++k) {
            const int ii  = i + k;
            float4 cur = vbuf[k];
            const int nxt = ii + 4;
            if (nxt < SEGLEN)
                vbuf[k] = emb4[(size_t)__shfl(xi, nxt, 64) * (V / 4) + c4];

            const int t   = tbase + ii;
            const int pos = b * T + t;
            nt_store4(&logits4[(size_t)pos * (V / 4) + c4], cur);
            S.x += cur.x; S.y += cur.y; S.z += cur.z; S.w += cur.w;
            const float inv = __shfl(invi, ii, 64);
            const float m0 = S.x * inv, m1 = S.y * inv, m2 = S.z * inv, m3 = S.w * inv;
            float e = __expf(m0) + __expf(m1) + __expf(m2) + __expf(m3);

            const int yc = __shfl(yi, ii, 64);
            const unsigned d = (unsigned)(yc - c0);
            if (d < 4u) {
                const float mv = (d == 0) ? m0 : (d == 1) ? m1 : (d == 2) ? m2 : m3;
                tval[pos] = mv;                       // unique writer per pos
            }
#pragma unroll
            for (int off = 32; off; off >>= 1) e += __shfl_xor(e, off, 64);
            if (lane == ii) myP = e;                  // butterfly leaves sum in all lanes
        }
    }
    // One coalesced 256B store per wave instead of 64 scattered 4B stores.
    P[(size_t)chunk * (B * T) + b * T + tbase + lane] = myP;
}

// Pass 3: per position sum chunk partials, nll = log(sum) - m[y]; mean via
// block reduce + one atomic per block. grid 32, block 256.
__global__ __launch_bounds__(256) void loss_kernel(
    const float* __restrict__ P, const float* __restrict__ tval,
    float* __restrict__ loss)
{
    const int pos = blockIdx.x * 256 + threadIdx.x;   // 0..8191
    float s = 0.f;
#pragma unroll
    for (int ch = 0; ch < NCHUNK; ++ch) s += P[(size_t)ch * (B * T) + pos];
    float nll = __logf(s) - tval[pos];

#pragma unroll
    for (int off = 32; off; off >>= 1) nll += __shfl_xor(nll, off, 64);
    __shared__ float red[4];
    const int wid = threadIdx.x >> 6;
    if ((threadIdx.x & 63) == 0) red[wid] = nll;
    __syncthreads();
    if (threadIdx.x == 0) {
        const float tot = red[0] + red[1] + red[2] + red[3];
        atomicAdd(loss, tot * (1.0f / (float)(B * T)));
    }
}

extern "C" void kernel_launch(void* const* d_in, const int* in_sizes, int n_in,
                              void* d_out, int out_size, void* d_ws, size_t ws_size,
                              hipStream_t stream) {
    const int*   x   = (const int*)d_in[0];
    const int*   y   = (const int*)d_in[1];
    const float* emb = (const float*)d_in[2];

    float* logits = (float*)d_out;                       // B*T*V floats
    float* loss   = logits + (size_t)B * T * V;          // 1 float

    // workspace: segsum [B][NSEG][V] (4 MB) | P [NCHUNK][B*T] (1 MB) | tval [B*T]
    float* segsum = (float*)d_ws;
    float* P      = segsum + (size_t)B * NSEG * V;
    float* tval   = P + (size_t)NCHUNK * B * T;

    hipMemsetAsync(loss, 0, sizeof(float), stream);
    sum_kernel<<<dim3(V / CSLICE, NSEG, B), 256, 0, stream>>>(emb, x, segsum);
    fused_kernel<<<dim3(NCHUNK / 4, NSEG, B), 256, 0, stream>>>(emb, x, y, segsum, logits, P, tval);
    loss_kernel<<<dim3(B * T / 256), 256, 0, stream>>>(P, tval, loss);
}